// Round 5
// baseline (269.849 us; speedup 1.0000x reference)
//
#include <hip/hip_runtime.h>
#include <cmath>

// R9: contiguous-stream staged MFMA gram.
// R4-R8: FIVE structurally different engines (4x VALU+LDS, 1x MFMA direct)
// all pinned at 95-116us; all pipes <25% busy; L3-warm iterations run the
// SAME ~95us as cold -> data residency irrelevant. The single invariant:
// every version had each wave-instruction touch 16 rows at exactly 4MB
// stride (power-of-2 alias: same L2 set for all 16 rows, fragmented 16B
// requests, 32 live pages/wave thrashing UTCL1). R9 keeps the R8 MFMA
// engine (passed, bit-identical numerics) but reads global CONTIGUOUSLY:
//  - per 128-col panel, each row's 512B window = 32 consecutive lanes x
//    16B in ONE instruction (<=2 streams/instr, full 128B lines).
//  - exp + bf16 hi/lo split at stage time -> XOR-swizzled LDS panel
//    (byte ^= (row&7)<<4, the verified G4 conflict fix).
//  - 4 waves take disjoint K=32 of the panel: 4 ds_read_b128 + the same
//    13-MFMA round-robin block as R8. z via ones-MFMA (layout-proof).
//  - panel t+1's global loads issued between the syncs (latency hidden).
//  - grid 1792 blocks = exactly 7/CU uniform; 16KB LDS reused by epilogue.

#define TPB 256
#define PANEL_K 128
#define PANELS 8
#define SPAN (PANEL_K * PANELS)       // 1024 cols per block
#define NSTEP 60

typedef short short8 __attribute__((ext_vector_type(8)));   // 8 x bf16 frag
typedef float f32x4 __attribute__((ext_vector_type(4)));    // MFMA acc

struct EpsList { float e[NSTEP]; };

struct GramArgs {
  const float* x0; const float* y0;
  const float* x1; const float* y1;
  const float* x2; const float* y2;
  int M0, M1, M2;
  int bs1, bs2, bsTot;
  float* partial;     // [block][800] contiguous fp32
  double* finalG;     // [3][800]
  int atomicMode;
};

__device__ __forceinline__ short f2bf_rne(float f) {
  unsigned u = __float_as_uint(f);
  u += 0x7FFFu + ((u >> 16) & 1u);
  return (short)(u >> 16);
}
__device__ __forceinline__ float bf2f(short h) {
  return __uint_as_float(((unsigned)(unsigned short)h) << 16);
}

__global__ __launch_bounds__(TPB) void gram_kernel(GramArgs A) {
  // [mat][plane(hi/lo)] panels of [16][128] bf16, 4KB each; 16KB total.
  // elem (row,col): byte = (mat*2+pl)*4096 + row*256 + 2*col, ^ (row&7)<<4.
  __shared__ __align__(16) char ldsRaw[16384];

  const int bid = blockIdx.x;
  int p, lb;
  if (bid >= A.bs2)      { p = 2; lb = bid - A.bs2; }
  else if (bid >= A.bs1) { p = 1; lb = bid - A.bs1; }
  else                   { p = 0; lb = bid; }
  const float* X = (p == 0) ? A.x0 : (p == 1) ? A.x1 : A.x2;
  const float* Y = (p == 0) ? A.y0 : (p == 1) ? A.y1 : A.y2;
  const int M    = (p == 0) ? A.M0 : (p == 1) ? A.M1 : A.M2;

  const int t    = threadIdx.x;
  const int w    = t >> 6;          // wave 0..3 -> k-window 32w..32w+31
  const int lane = t & 63;

  // loader mapping: mat = t>>7; within mat, group lw32 = (t&127)>>5 owns
  // rows 4*lw32..4*lw32+3; lane32 = t&31 -> 16B segment at col 4*lane32.
  const int lmat = t >> 7;
  const int lw32 = (t & 127) >> 5;
  const int l32  = t & 31;
  const float* LP = lmat ? Y : X;
  const size_t cbase = (size_t)lb * SPAN + 4 * l32;

  // MFMA mapping (identical to R8, which passed): r=lane&15, kg=lane>>4.
  const int r  = lane & 15;
  const int kg = lane >> 4;

  f32x4 aXY = {0.f, 0.f, 0.f, 0.f};
  f32x4 aXX = {0.f, 0.f, 0.f, 0.f};
  f32x4 aYY = {0.f, 0.f, 0.f, 0.f};
  f32x4 aZX = {0.f, 0.f, 0.f, 0.f};
  f32x4 aZY = {0.f, 0.f, 0.f, 0.f};
  short8 ones;
  #pragma unroll
  for (int j = 0; j < 8; ++j) ones[j] = (short)0x3F80;   // bf16 1.0

  float4 L[4];
  auto issue = [&](int pnl) {
    const size_t cb = cbase + (size_t)pnl * PANEL_K;
    #pragma unroll
    for (int q = 0; q < 4; ++q)
      L[q] = *reinterpret_cast<const float4*>(LP + (size_t)(4 * lw32 + q) * M + cb);
  };
  auto stage = [&]() {
    #pragma unroll
    for (int q = 0; q < 4; ++q) {
      const int row = 4 * lw32 + q;
      const float e0 = __expf(L[q].x), e1 = __expf(L[q].y);
      const float e2 = __expf(L[q].z), e3 = __expf(L[q].w);
      const short h0 = f2bf_rne(e0), h1 = f2bf_rne(e1);
      const short h2 = f2bf_rne(e2), h3 = f2bf_rne(e3);
      const short g0 = f2bf_rne(e0 - bf2f(h0)), g1 = f2bf_rne(e1 - bf2f(h1));
      const short g2 = f2bf_rne(e2 - bf2f(h2)), g3 = f2bf_rne(e3 - bf2f(h3));
      const int off = row * 256 + ((l32 * 8) ^ ((row & 7) << 4));
      *reinterpret_cast<short4*>(ldsRaw + (lmat * 2 + 0) * 4096 + off) =
          make_short4(h0, h1, h2, h3);
      *reinterpret_cast<short4*>(ldsRaw + (lmat * 2 + 1) * 4096 + off) =
          make_short4(g0, g1, g2, g3);
    }
  };
  const int rdoff = r * 256 + ((64 * w + 16 * kg) ^ ((r & 7) << 4));
  auto mfma_panel = [&]() {
    const short8 hx = *reinterpret_cast<const short8*>(ldsRaw +    0 + rdoff);
    const short8 lx = *reinterpret_cast<const short8*>(ldsRaw + 4096 + rdoff);
    const short8 hy = *reinterpret_cast<const short8*>(ldsRaw + 8192 + rdoff);
    const short8 ly = *reinterpret_cast<const short8*>(ldsRaw + 12288 + rdoff);
    // round-robin over the 5 accumulators -> dep distance >= 5
    aXY = __builtin_amdgcn_mfma_f32_16x16x32_bf16(hx, hy, aXY, 0, 0, 0);
    aXX = __builtin_amdgcn_mfma_f32_16x16x32_bf16(hx, hx, aXX, 0, 0, 0);
    aYY = __builtin_amdgcn_mfma_f32_16x16x32_bf16(hy, hy, aYY, 0, 0, 0);
    aZX = __builtin_amdgcn_mfma_f32_16x16x32_bf16(hx, ones, aZX, 0, 0, 0);
    aZY = __builtin_amdgcn_mfma_f32_16x16x32_bf16(hy, ones, aZY, 0, 0, 0);
    aXY = __builtin_amdgcn_mfma_f32_16x16x32_bf16(hx, ly, aXY, 0, 0, 0);
    aXX = __builtin_amdgcn_mfma_f32_16x16x32_bf16(hx, lx, aXX, 0, 0, 0);
    aYY = __builtin_amdgcn_mfma_f32_16x16x32_bf16(hy, ly, aYY, 0, 0, 0);
    aZX = __builtin_amdgcn_mfma_f32_16x16x32_bf16(lx, ones, aZX, 0, 0, 0);
    aZY = __builtin_amdgcn_mfma_f32_16x16x32_bf16(ly, ones, aZY, 0, 0, 0);
    aXY = __builtin_amdgcn_mfma_f32_16x16x32_bf16(lx, hy, aXY, 0, 0, 0);
    aXX = __builtin_amdgcn_mfma_f32_16x16x32_bf16(lx, hx, aXX, 0, 0, 0);
    aYY = __builtin_amdgcn_mfma_f32_16x16x32_bf16(ly, hy, aYY, 0, 0, 0);
  };

  issue(0);
  #pragma unroll 1
  for (int pnl = 0; pnl < PANELS; ++pnl) {
    stage();                          // vmcnt wait + exp/split + LDS writes
    __syncthreads();
    if (pnl + 1 < PANELS) issue(pnl + 1);   // in flight under MFMA phase
    mfma_panel();
    __syncthreads();                  // LDS reads done before next stage
  }

  // C layout (HW-verified, R8 passed): col = lane&15, row = (lane>>4)*4+j.
  if (A.atomicMode) {
    double* fin = A.finalG + (size_t)p * 800;
    #pragma unroll
    for (int j = 0; j < 4; ++j) {
      const int ib = (4 * kg + j) * 16 + r;
      atomicAdd(&fin[ib],       (double)aXY[j]);
      atomicAdd(&fin[256 + ib], (double)aXX[j]);
      atomicAdd(&fin[512 + ib], (double)aYY[j]);
    }
    if (r == 0) {
      #pragma unroll
      for (int j = 0; j < 4; ++j) {
        atomicAdd(&fin[768 + 4 * kg + j], (double)aZX[j]);
        atomicAdd(&fin[784 + 4 * kg + j], (double)aZY[j]);
      }
    }
    return;
  }

  // epilogue: reuse the panel LDS as [4][800] fp32 (12.8KB <= 16KB).
  float* sB = reinterpret_cast<float*>(ldsRaw);
  float* b = sB + w * 800;
  #pragma unroll
  for (int j = 0; j < 4; ++j) {
    const int ib = (4 * kg + j) * 16 + r;
    b[ib]       = aXY[j];
    b[256 + ib] = aXX[j];
    b[512 + ib] = aYY[j];
  }
  if (r == 0) {
    #pragma unroll
    for (int j = 0; j < 4; ++j) {
      b[768 + 4 * kg + j] = aZX[j];
      b[784 + 4 * kg + j] = aZY[j];
    }
  }
  __syncthreads();
  if (t < 200) {
    const int o4 = 4 * t;
    const float4 v0 = *reinterpret_cast<const float4*>(sB + o4);
    const float4 v1 = *reinterpret_cast<const float4*>(sB + 800 + o4);
    const float4 v2 = *reinterpret_cast<const float4*>(sB + 1600 + o4);
    const float4 v3 = *reinterpret_cast<const float4*>(sB + 2400 + o4);
    const float4 o = make_float4((v0.x + v1.x) + (v2.x + v3.x),
                                 (v0.y + v1.y) + (v2.y + v3.y),
                                 (v0.z + v1.z) + (v2.z + v3.z),
                                 (v0.w + v1.w) + (v2.w + v3.w));
    *reinterpret_cast<float4*>(A.partial + (size_t)bid * 800 + o4) = o;
  }
}

// 16 partial-rows per block, coalesced contiguous reads (3200 B rows),
// fp64 register accumulation, one atomicAdd per value.
__global__ __launch_bounds__(256) void reduce_kernel(const float* __restrict__ partial,
                                                     double* __restrict__ finalG,
                                                     int nb0, int nb1, int nb2) {
  const int c0 = (nb0 + 15) >> 4, c1 = (nb1 + 15) >> 4;
  const int b = blockIdx.x;
  int p, r0, pstart, cnt;
  if (b < c0)           { p = 0; r0 = b << 4;             pstart = 0;         cnt = nb0; }
  else if (b < c0 + c1) { p = 1; r0 = (b - c0) << 4;      pstart = nb0;       cnt = nb1; }
  else                  { p = 2; r0 = (b - c0 - c1) << 4; pstart = nb0 + nb1; cnt = nb2; }
  const int rows = min(16, cnt - r0);
  const float* src = partial + (size_t)(pstart + r0) * 800;
  const int tt = threadIdx.x;
  double s0 = 0.0, s1 = 0.0, s2 = 0.0, s3 = 0.0;
  #pragma unroll 1
  for (int rr = 0; rr < rows; ++rr) {
    const float* row = src + (size_t)rr * 800;
    s0 += (double)row[tt];
    s1 += (double)row[tt + 256];
    s2 += (double)row[tt + 512];
    if (tt < 32) s3 += (double)row[768 + tt];
  }
  double* fin = finalG + (size_t)p * 800;
  atomicAdd(&fin[tt], s0);
  atomicAdd(&fin[tt + 256], s1);
  atomicAdd(&fin[tt + 512], s2);
  if (tt < 32) atomicAdd(&fin[768 + tt], s3);
}

__device__ __forceinline__ float expm1_poly(float d) {
  float pp = 1.0f / 120.0f;
  pp = fmaf(pp, d, 1.0f / 24.0f);
  pp = fmaf(pp, d, 1.0f / 6.0f);
  pp = fmaf(pp, d, 0.5f);
  return fmaf(d * d, pp, d);
}
__device__ __forceinline__ float log1p_poly(float w) {
  float pp = -1.0f / 6.0f;
  pp = fmaf(pp, w, 1.0f / 5.0f);
  pp = fmaf(pp, w, -1.0f / 4.0f);
  pp = fmaf(pp, w, 1.0f / 3.0f);
  pp = fmaf(pp, w, -0.5f);
  return fmaf(w * w, pp, w);
}

// 6 waves in ONE block: wave 2p = (f,g) chains of pair p ; 2p+1 = (a,b)
// self chains. finalize folded in after __syncthreads.
__global__ __launch_bounds__(384) void sinkhorn_kernel(const double* __restrict__ finalG,
                                                       float* __restrict__ out, EpsList E) {
  const int grp  = threadIdx.x >> 6;
  const int p    = grp >> 1;
  const int half = grp & 1;
  const int lane = threadIdx.x & 63;
  const int pot  = lane >> 5;
  const int i    = (lane >> 1) & 15;
  const int jh   = lane & 1;
  const double* G = finalG + p * 800;

  float Crow[8];
  #pragma unroll
  for (int jj = 0; jj < 8; ++jj) {
    const int j = jh * 8 + jj;
    double Cv;
    if (half == 0) {
      const int rr = (pot == 0) ? i : j;
      const int cc = (pot == 0) ? j : i;
      const double zr = G[768 + rr], zc = G[784 + cc];
      const double sr = G[256 + 17 * rr] / (zr * zr);
      const double sc = G[512 + 17 * cc] / (zc * zc);
      Cv = 0.5 * (sr + sc) - G[16 * rr + cc] / (zr * zc);
    } else if (pot == 0) {
      const double zi_ = G[768 + i], zj_ = G[768 + j];
      const double si_ = G[256 + 17 * i] / (zi_ * zi_);
      const double sj_ = G[256 + 17 * j] / (zj_ * zj_);
      Cv = 0.5 * (si_ + sj_) - G[256 + 16 * i + j] / (zi_ * zj_);
    } else {
      const double zi_ = G[784 + i], zj_ = G[784 + j];
      const double si_ = G[512 + 17 * i] / (zi_ * zi_);
      const double sj_ = G[512 + 17 * j] / (zj_ * zj_);
      Cv = 0.5 * (si_ + sj_) - G[512 + 16 * i + j] / (zi_ * zj_);
    }
    Crow[jj] = (float)Cv;
  }

  const int srcBase = (half == 0) ? ((pot == 0) ? 32 : 0)
                                  : ((pot == 0) ? 0 : 32);
  float h = 0.0f;

  #pragma unroll 1
  for (int n = 0; n < NSTEP; ++n) {
    const float eps  = E.e[n];
    const float inve = 1.0f / eps;
    float q = 0.0f;
    #pragma unroll
    for (int jj = 0; jj < 8; ++jj) {
      const float hj = __shfl(h, srcBase + 2 * (jh * 8 + jj));
      q += expm1_poly((hj - Crow[jj]) * inve);
    }
    q += __shfl_xor(q, 1);
    const float val = -eps * log1p_poly(q * (1.0f / 16.0f));
    h = 0.5f * (h + val);
  }
  {
    const float eps  = 0.0025f;
    const float inve = 1.0f / eps;
    float q = 0.0f;
    #pragma unroll
    for (int jj = 0; jj < 8; ++jj) {
      const float hj = __shfl(h, srcBase + 2 * (jh * 8 + jj));
      q += expm1_poly((hj - Crow[jj]) * inve);
    }
    q += __shfl_xor(q, 1);
    h = -eps * log1p_poly(q * (1.0f / 16.0f));
  }
  float sAcc = h;
  #pragma unroll
  for (int d = 1; d <= 32; d <<= 1) sAcc += __shfl_xor(sAcc, d);

  __shared__ double res[6];
  if (lane == 0) res[grp] = (double)(sAcc * (1.0f / 32.0f));
  __syncthreads();
  if (threadIdx.x == 0) {
    const double v = (res[0] - res[1]) + (res[2] - res[3]) + (res[4] - res[5]);
    out[0] = (float)(v / 3.0);
  }
}

extern "C" void kernel_launch(void* const* d_in, const int* in_sizes, int n_in,
                              void* d_out, int out_size, void* d_ws, size_t ws_size,
                              hipStream_t stream) {
  (void)n_in; (void)out_size;
  int idx[6] = {0, 1, 2, 3, 4, 5};
  for (int a = 1; a < 6; ++a) {
    const int key = idx[a];
    int b = a - 1;
    while (b >= 0 && in_sizes[idx[b]] < in_sizes[key]) { idx[b + 1] = idx[b]; --b; }
    idx[b + 1] = key;
  }

  const float* xs[3]; const float* ys[3]; int Ms[3]; int nb[3];
  for (int p = 0; p < 3; ++p) {
    xs[p] = (const float*)d_in[idx[2 * p]];
    ys[p] = (const float*)d_in[idx[2 * p + 1]];
    Ms[p] = in_sizes[idx[2 * p]] / 16;
    nb[p] = Ms[p] / SPAN;
  }
  const int totalBlocks = nb[0] + nb[1] + nb[2];

  const size_t partialBytes = (size_t)totalBlocks * 800 * sizeof(float);
  const size_t finalBytes   = (size_t)2400 * sizeof(double);
  const bool partialMode    = (ws_size >= partialBytes + finalBytes);

  char* wsb      = (char*)d_ws;
  float* partial = partialMode ? (float*)wsb : nullptr;
  double* finalG = (double*)(wsb + (partialMode ? partialBytes : 0));

  hipMemsetAsync(finalG, 0, finalBytes, stream);

  GramArgs A;
  A.x0 = xs[0]; A.y0 = ys[0];
  A.x1 = xs[1]; A.y1 = ys[1];
  A.x2 = xs[2]; A.y2 = ys[2];
  A.M0 = Ms[0]; A.M1 = Ms[1]; A.M2 = Ms[2];
  A.bs1 = nb[0]; A.bs2 = nb[0] + nb[1]; A.bsTot = totalBlocks;
  A.partial = partial; A.finalG = finalG;
  A.atomicMode = partialMode ? 0 : 1;

  gram_kernel<<<dim3(totalBlocks), dim3(TPB), 0, stream>>>(A);
  if (partialMode) {
    const int rb = ((nb[0] + 15) / 16) + ((nb[1] + 15) / 16) + ((nb[2] + 15) / 16);
    reduce_kernel<<<dim3(rb), dim3(256), 0, stream>>>(partial, finalG, nb[0], nb[1], nb[2]);
  }

  EpsList E;
  const double base = 0.95 * 0.95;
  for (int n = 0; n < NSTEP; ++n) {
    double v = pow(base, (double)n);
    if (v < 0.0025) v = 0.0025;
    E.e[n] = (float)v;
  }
  sinkhorn_kernel<<<dim3(1), dim3(384), 0, stream>>>(finalG, (float*)d_out, E);
}